// Round 16
// baseline (135.067 us; speedup 1.0000x reference)
//
#include <hip/hip_runtime.h>
#include <stdint.h>

#define IN_SIZE 224
#define KER 5
#define IN_CH 16
#define OUT_CH 64
#define NH 220
#define NB_TILES (NH * NH)       // 48400
#define XCH (IN_SIZE * IN_SIZE)  // 50176
#define OUT_PLANE NB_TILES
#define KP2 51200                // padded K for gemm
#define XS 52224                 // per-plane stride in shifted-x copies
#define XTROWS 50304             // xT rows (XCH + pad for tap overhang)
#define LR_OVER_NB ((float)(0.005 / 48400.0))
#define GAMMA_F 0.99f
#define ONE_MINUS_GAMMA 0.01f
#define EPS_F 0.01f

#define NCHUNK 160
#define CK 320                   // 10 steps of BK=32
#define PSTRIDE (64 * 512)

typedef __attribute__((ext_vector_type(8))) short short8;
typedef __attribute__((ext_vector_type(4))) float floatx4;

__device__ inline uint16_t f2bf(float f) {
    uint32_t u = __float_as_uint(f);
    return (uint16_t)((u + 0x7FFFu + ((u >> 16) & 1u)) >> 16);
}
__device__ inline float bf2f(uint16_t h) { return __uint_as_float((uint32_t)h << 16); }

// ---- Kernel 0: FUSED prep: 5 kj-shifted x copies + yb pads + ones + xT hi/lo + W repack ----
__global__ __launch_bounds__(256) void prep_kernel(const float* __restrict__ x,
                                                   uint16_t* __restrict__ xs,
                                                   uint16_t* __restrict__ yb,
                                                   uint16_t* __restrict__ ones,
                                                   uint16_t* __restrict__ xth,
                                                   uint16_t* __restrict__ xtl,
                                                   const float* __restrict__ W,
                                                   uint16_t* __restrict__ wrh,
                                                   uint16_t* __restrict__ wrl) {
    int blk = blockIdx.x;
    if (blk < 4080) {  // shifted copies / pads / ones
        int t = blk * 256 + threadIdx.x;
        const int perq = XS / 4;  // 13056
        if (t < 5 * 16 * perq) {
            int kj = t / (16 * perq);
            int rem = t - kj * (16 * perq);
            int c = rem / perq;
            int q = (rem - c * perq) * 4;
            int base = c * XCH;
            ushort4 o;
            int i0 = q + kj;     o.x = f2bf(x[base + (i0 < XCH ? i0 : XCH - 1)]);
            int i1 = q + kj + 1; o.y = f2bf(x[base + (i1 < XCH ? i1 : XCH - 1)]);
            int i2 = q + kj + 2; o.z = f2bf(x[base + (i2 < XCH ? i2 : XCH - 1)]);
            int i3 = q + kj + 3; o.w = f2bf(x[base + (i3 < XCH ? i3 : XCH - 1)]);
            *(ushort4*)(xs + (kj * 16 + c) * XS + q) = o;
        }
        ushort4 z = {0, 0, 0, 0};
        if (t < 64 * 480) {  // zero yb K-tail [49280,51200)
            int r = t / 480, q = (t - r * 480) * 4;
            *(ushort4*)(yb + r * KP2 + 49280 + q) = z;
        }
        if (t < 64 * 220) {  // zero yb j-pad cols 220..223
            int o = t / 220, i = t - o * 220;
            *(ushort4*)(yb + o * KP2 + i * 224 + 220) = z;
        }
        if (t < 12816) {  // bf16 ones (51264 entries)
            ushort4 o1 = {0x3F80, 0x3F80, 0x3F80, 0x3F80};
            ((ushort4*)ones)[t] = o1;
        }
    } else if (blk < 4080 + 197) {  // xT hi/lo
        int addr = (blk - 4080) * 256 + threadIdx.x;
        if (addr >= XTROWS) return;
        uint32_t dh[8], dl[8];
        if (addr < XCH) {
#pragma unroll
            for (int q = 0; q < 8; q++) {
                float v0 = x[(2 * q) * XCH + addr];
                float v1 = x[(2 * q + 1) * XCH + addr];
                uint16_t h0 = f2bf(v0), h1 = f2bf(v1);
                uint16_t l0 = f2bf(v0 - bf2f(h0)), l1 = f2bf(v1 - bf2f(h1));
                dh[q] = (uint32_t)h0 | ((uint32_t)h1 << 16);
                dl[q] = (uint32_t)l0 | ((uint32_t)l1 << 16);
            }
        } else {
#pragma unroll
            for (int q = 0; q < 8; q++) { dh[q] = 0u; dl[q] = 0u; }
        }
        *(uint4*)(xth + addr * 16) = make_uint4(dh[0], dh[1], dh[2], dh[3]);
        *(uint4*)(xth + addr * 16 + 8) = make_uint4(dh[4], dh[5], dh[6], dh[7]);
        *(uint4*)(xtl + addr * 16) = make_uint4(dl[0], dl[1], dl[2], dl[3]);
        *(uint4*)(xtl + addr * 16 + 8) = make_uint4(dl[4], dl[5], dl[6], dl[7]);
    } else {  // W fragment-packed: wrp[t][ocg][lane][j]
        int idx = (blk - 4080 - 197) * 256 + threadIdx.x;
        if (idx >= 13 * 4 * 64 * 8) return;
        int j = idx & 7;
        int lane = (idx >> 3) & 63;
        int ocg = (idx >> 9) & 3;
        int t = idx >> 11;
        int k = (lane >> 4) * 8 + j;
        int s = k >> 4, c = k & 15;
        int oc = 16 * ocg + (lane & 15);
        int tap = 2 * t + s;
        float v = (tap < 25) ? W[oc * 400 + c * 25 + tap] : 0.f;
        uint16_t h = f2bf(v);
        wrh[idx] = h;
        wrl[idx] = f2bf(v - bf2f(h));
    }
}

// ---- Kernel 1: conv MFMA + inhibition, 32 positions/block (1540 blocks = 6/CU) ----
__global__ __launch_bounds__(256) void conv_inhib_kernel(const uint16_t* __restrict__ xth,
                                                         const uint16_t* __restrict__ xtl,
                                                         const uint16_t* __restrict__ wrh,
                                                         const uint16_t* __restrict__ wrl,
                                                         float* __restrict__ out,
                                                         uint16_t* __restrict__ yb) {
    const int lane = threadIdx.x & 63;
    const int w = threadIdx.x >> 6;   // oc-group: rows 16w..16w+15
    const int l15 = lane & 15;
    const int quad = lane >> 4;
    const int P0 = blockIdx.x * 32;
    const int c0 = (quad & 1) * 8;
    const int sq = quad >> 1;

    floatx4 acc[2];
#pragma unroll
    for (int g = 0; g < 2; g++) acc[g] = (floatx4){0.f, 0.f, 0.f, 0.f};

#pragma unroll
    for (int t = 0; t < 13; t++) {
        short8 ah = *(const short8*)(wrh + ((t * 4 + w) * 64 + lane) * 8);
        short8 al = *(const short8*)(wrl + ((t * 4 + w) * 64 + lane) * 8);
        const int tap0 = 2 * t, tap1 = 2 * t + 1;
        const int o0 = (tap0 / 5) * 224 + (tap0 % 5);
        const int o1 = (tap1 <= 24) ? (tap1 / 5) * 224 + (tap1 % 5) : 0;
        const int off = sq ? o1 : o0;
#pragma unroll
        for (int g = 0; g < 2; g++) {
            int P = P0 + 16 * g + l15;
            short8 bh = *(const short8*)(xth + (P + off) * 16 + c0);
            short8 bl = *(const short8*)(xtl + (P + off) * 16 + c0);
            acc[g] = __builtin_amdgcn_mfma_f32_16x16x32_bf16(ah, bh, acc[g], 0, 0, 0);
            acc[g] = __builtin_amdgcn_mfma_f32_16x16x32_bf16(ah, bl, acc[g], 0, 0, 0);
            acc[g] = __builtin_amdgcn_mfma_f32_16x16x32_bf16(al, bh, acc[g], 0, 0, 0);
        }
    }

    __shared__ float wmax[4][32];
    float pmax[2];
#pragma unroll
    for (int g = 0; g < 2; g++) {
        float mx = fmaxf(fmaxf(acc[g][0], acc[g][1]), fmaxf(acc[g][2], acc[g][3]));
        mx = fmaxf(mx, 0.f);
        mx = fmaxf(mx, __shfl_xor(mx, 16));
        mx = fmaxf(mx, __shfl_xor(mx, 32));
        pmax[g] = mx;
    }
    if (quad == 0) {
#pragma unroll
        for (int g = 0; g < 2; g++) wmax[w][g * 16 + l15] = pmax[g];
    }
    __syncthreads();

#pragma unroll
    for (int g = 0; g < 2; g++) {
        int P = P0 + 16 * g + l15;
        int i = P / 224;
        int j = P - i * 224;
        bool valid = j < NH;
        float mx = fmaxf(fmaxf(wmax[0][g * 16 + l15], wmax[1][g * 16 + l15]),
                         fmaxf(wmax[2][g * 16 + l15], wmax[3][g * 16 + l15]));
        float inv = 1.f / (mx + 1e-9f);
#pragma unroll
        for (int r = 0; r < 4; r++) {
            float tv = fmaxf(acc[g][r], 0.f) * inv;
            float t2 = tv * tv;
            tv = t2 * t2 * tv;
            if (valid) {
                int oc = 16 * w + quad * 4 + r;
                out[oc * OUT_PLANE + i * NH + j] = tv;
                yb[oc * KP2 + P] = f2bf(tv);
            }
        }
    }
}

// ---- Kernel 2: LDS-staged GEMM, 10 steps of BK=32, grid (8,160) = 1280 blocks (5/CU) ----
__global__ __launch_bounds__(256) void gemm_kernel(const uint16_t* __restrict__ yb,
                                                   const uint16_t* __restrict__ xs,
                                                   const uint16_t* __restrict__ ones,
                                                   float* __restrict__ Mpart) {
    __shared__ uint16_t As[2][64 * 40];
    __shared__ uint16_t Bs[2][64 * 40];
    const int tid = threadIdx.x;
    const int lane = tid & 63;
    const int w = tid >> 6;
    const int l15 = lane & 15;
    const int quad = lane >> 4;
    const int kg = quad * 8;
    const int b = blockIdx.x;
    const int xcd = b & 7;
    const int t8 = b >> 3;
    const int ntile = t8 & 7;
    const int chunk = xcd + 8 * (t8 >> 3);   // 0..159
    const int k0 = chunk * CK;

    const int sr = tid >> 2;
    const int sseg = (tid & 3) * 8;
    const uint16_t* pa = yb + sr * KP2 + k0 + sseg;

    int n_g = ntile * 64 + sr;
    const uint16_t* pbase;
    if (n_g < 400) {
        int c = n_g / 25;
        int r = n_g - 25 * c;
        int ki = r / 5;
        int kj = r - 5 * ki;
        pbase = xs + (kj * 16 + c) * XS + ki * 224;
    } else if (n_g < 464) {
        pbase = yb + (n_g - 400) * KP2;
    } else if (n_g == 464) {
        pbase = ones;
    } else {
        pbase = yb;  // dead column
    }
    const uint16_t* pb = pbase + k0 + sseg;

    floatx4 acc[4];
#pragma unroll
    for (int i = 0; i < 4; i++) acc[i] = (floatx4){0.f, 0.f, 0.f, 0.f};

    uint4 ra = *(const uint4*)pa;
    uint4 rb = *(const uint4*)pb;

#pragma unroll
    for (int s = 0; s < 10; s++) {
        const int p = s & 1;
        *(uint4*)&As[p][sr * 40 + sseg] = ra;
        *(uint4*)&Bs[p][sr * 40 + sseg] = rb;
        __syncthreads();
        if (s + 1 < 10) {
            pa += 32;
            pb += 32;
            ra = *(const uint4*)pa;
            rb = *(const uint4*)pb;
        }
        short8 af = *(const short8*)&As[p][(16 * w + l15) * 40 + kg];
#pragma unroll
        for (int ng = 0; ng < 4; ng++) {
            short8 bf = *(const short8*)&Bs[p][(16 * ng + l15) * 40 + kg];
            acc[ng] = __builtin_amdgcn_mfma_f32_16x16x32_bf16(af, bf, acc[ng], 0, 0, 0);
        }
        __syncthreads();
    }

    float* dst = Mpart + chunk * PSTRIDE;
#pragma unroll
    for (int ng = 0; ng < 4; ng++) {
        int col = ntile * 64 + ng * 16 + l15;
        if (col < 465) {
#pragma unroll
            for (int r = 0; r < 4; r++)
                dst[(16 * w + quad * 4 + r) * 512 + col] = acc[ng][r];
        }
    }
}

// ---- Kernel 3: FUSED reduce + finalize: Mpart -> Wout, expout ----
__global__ __launch_bounds__(256) void finalize_w_kernel(const float* __restrict__ W,
                                                         const float* __restrict__ Mpart,
                                                         const float* __restrict__ exp_avg,
                                                         float* __restrict__ Wout,
                                                         float* __restrict__ expout) {
    __shared__ float gfps[OUT_CH];
    __shared__ float ytys[2][OUT_CH];
    const int tid = threadIdx.x;
    const int bid = blockIdx.x;
    const int first_o = (bid * 256) / 400;

    if (tid < OUT_CH) {  // colsum -> exp_new -> gfp
        int o = tid;
        float cs = 0.f;
#pragma unroll 8
        for (int ch = 0; ch < NCHUNK; ch++) cs += Mpart[ch * PSTRIDE + o * 512 + 464];
        float e = GAMMA_F * exp_avg[o] + ONE_MINUS_GAMMA * (cs / (float)NB_TILES);
        float s = e;
        for (int off = 32; off; off >>= 1) s += __shfl_down(s, off);
        s = __shfl(s, 0);
        float A = e / (s / (float)OUT_CH);
        gfps[o] = EPS_F * tanhf(-EPS_F * (A - 1.f)) + 1.f;
        if (bid == 0) expout[o] = e;
    }
    if (tid >= 128) {  // the <=2 yty rows this block needs
        int t = tid - 128;
        int orow = first_o + (t >> 6);
        int k = t & 63;
        float s = 0.f;
        if (orow < OUT_CH) {
#pragma unroll 8
            for (int ch = 0; ch < NCHUNK; ch++) s += Mpart[ch * PSTRIDE + orow * 512 + 400 + k];
        }
        ytys[t >> 6][k] = s;
    }
    __syncthreads();

    int idx = bid * 256 + tid;
    int o = idx / 400;
    int q = idx - o * 400;
    float Mv = 0.f;
#pragma unroll 8
    for (int ch = 0; ch < NCHUNK; ch++) Mv += Mpart[ch * PSTRIDE + o * 512 + q];
    const float* yrow = ytys[o - first_o];
    float dot = 0.f;
#pragma unroll 8
    for (int k = 0; k < OUT_CH; k++) dot = fmaf(yrow[k], W[k * 400 + q], dot);
    float wv = W[idx] + LR_OVER_NB * (Mv - dot);
    wv = fmaxf(wv, 0.f);
    float gp = gfps[o];
    float pos = (wv > 0.f ? wv : 0.f) * gp;
    float neg = (wv < 0.f ? wv : 0.f) / gp;
    Wout[idx] = pos + neg;
}

extern "C" void kernel_launch(void* const* d_in, const int* in_sizes, int n_in,
                              void* d_out, int out_size, void* d_ws, size_t ws_size,
                              hipStream_t stream) {
    const float* x = (const float*)d_in[0];
    const float* W = (const float*)d_in[1];
    const float* exp_avg = (const float*)d_in[2];
    float* out = (float*)d_out;

    float* wsf = (float*)d_ws;
    float* Mpart = wsf + 29760;                 // 160*32768 floats = 21 MB
    // conv-side buffers overlaid on Mpart (dead until gemm writes it)
    uint16_t* xth = (uint16_t*)Mpart;           // 50304*16
    uint16_t* xtl = xth + XTROWS * 16;          // 50304*16
    uint16_t* wrh = xtl + XTROWS * 16;          // 26624
    uint16_t* wrl = wrh + 26624;                // 26624
    uint16_t* ybf = (uint16_t*)(wsf + 29760 + NCHUNK * PSTRIDE);  // 64*51200 bf16
    uint16_t* xsb = ybf + OUT_CH * KP2;                            // 5*16*52224 bf16
    uint16_t* ones = xsb + 5 * 16 * XS;                            // 51264 bf16

    float* Wout = out + OUT_CH * OUT_PLANE;
    float* expout = Wout + OUT_CH * IN_CH * KER * KER;

    prep_kernel<<<4080 + 197 + 104, 256, 0, stream>>>(x, xsb, ybf, ones, xth, xtl, W, wrh, wrl);
    conv_inhib_kernel<<<1540, 256, 0, stream>>>(xth, xtl, wrh, wrl, out, ybf);
    gemm_kernel<<<1280, 256, 0, stream>>>(ybf, xsb, ones, Mpart);
    finalize_w_kernel<<<100, 256, 0, stream>>>(W, Mpart, exp_avg, Wout, expout);
}

// Round 17
// 124.131 us; speedup vs baseline: 1.0881x; 1.0881x over previous
//
#include <hip/hip_runtime.h>
#include <stdint.h>

#define IN_SIZE 224
#define KER 5
#define IN_CH 16
#define OUT_CH 64
#define NH 220
#define NB_TILES (NH * NH)       // 48400
#define XCH (IN_SIZE * IN_SIZE)  // 50176
#define OUT_PLANE NB_TILES
#define KP2 51200                // padded K for gemm
#define XTROWS 50304             // xT rows (XCH + pad for tap overhang)
#define XCPAD 2048               // xc tail pad (zeroed)
#define LR_OVER_NB ((float)(0.005 / 48400.0))
#define GAMMA_F 0.99f
#define ONE_MINUS_GAMMA 0.01f
#define EPS_F 0.01f

#define NCHUNK 64
#define CK 800                   // 25 steps of BK=32
#define PSTRIDE (64 * 512)

typedef __attribute__((ext_vector_type(8))) short short8;
typedef __attribute__((ext_vector_type(4))) float floatx4;

__device__ inline uint16_t f2bf(float f) {
    uint32_t u = __float_as_uint(f);
    return (uint16_t)((u + 0x7FFFu + ((u >> 16) & 1u)) >> 16);
}
__device__ inline float bf2f(uint16_t h) { return __uint_as_float((uint32_t)h << 16); }

// ---- Kernel 0: FUSED prep: compact bf16 xc + yb pads + ones + xT hi/lo + W repack ----
__global__ __launch_bounds__(256) void prep_kernel(const float* __restrict__ x,
                                                   uint16_t* __restrict__ xc,
                                                   uint16_t* __restrict__ yb,
                                                   uint16_t* __restrict__ ones,
                                                   uint16_t* __restrict__ xth,
                                                   uint16_t* __restrict__ xtl,
                                                   const float* __restrict__ W,
                                                   uint16_t* __restrict__ wrh,
                                                   uint16_t* __restrict__ wrl) {
    int blk = blockIdx.x;
    if (blk < 784) {  // compact bf16 x copy + pads + ones
        int t = blk * 256 + threadIdx.x;
        if (t < 16 * XCH / 4) {  // 200704 ushort4
            float4 v = ((const float4*)x)[t];
            ushort4 o;
            o.x = f2bf(v.x); o.y = f2bf(v.y); o.z = f2bf(v.z); o.w = f2bf(v.w);
            ((ushort4*)xc)[t] = o;
        }
        ushort4 z = {0, 0, 0, 0};
        if (t < XCPAD / 4) {  // zero xc tail pad
            ((ushort4*)(xc + 16 * XCH))[t] = z;
        }
        if (t < 64 * 480) {  // zero yb K-tail [49280,51200)
            int r = t / 480, q = (t - r * 480) * 4;
            *(ushort4*)(yb + r * KP2 + 49280 + q) = z;
        }
        if (t < 64 * 220) {  // zero yb j-pad cols 220..223
            int o = t / 220, i = t - o * 220;
            *(ushort4*)(yb + o * KP2 + i * 224 + 220) = z;
        }
        if (t < 12816) {  // bf16 ones (51264 entries)
            ushort4 o1 = {0x3F80, 0x3F80, 0x3F80, 0x3F80};
            ((ushort4*)ones)[t] = o1;
        }
    } else if (blk < 784 + 197) {  // xT hi/lo
        int addr = (blk - 784) * 256 + threadIdx.x;
        if (addr >= XTROWS) return;
        uint32_t dh[8], dl[8];
        if (addr < XCH) {
#pragma unroll
            for (int q = 0; q < 8; q++) {
                float v0 = x[(2 * q) * XCH + addr];
                float v1 = x[(2 * q + 1) * XCH + addr];
                uint16_t h0 = f2bf(v0), h1 = f2bf(v1);
                uint16_t l0 = f2bf(v0 - bf2f(h0)), l1 = f2bf(v1 - bf2f(h1));
                dh[q] = (uint32_t)h0 | ((uint32_t)h1 << 16);
                dl[q] = (uint32_t)l0 | ((uint32_t)l1 << 16);
            }
        } else {
#pragma unroll
            for (int q = 0; q < 8; q++) { dh[q] = 0u; dl[q] = 0u; }
        }
        *(uint4*)(xth + addr * 16) = make_uint4(dh[0], dh[1], dh[2], dh[3]);
        *(uint4*)(xth + addr * 16 + 8) = make_uint4(dh[4], dh[5], dh[6], dh[7]);
        *(uint4*)(xtl + addr * 16) = make_uint4(dl[0], dl[1], dl[2], dl[3]);
        *(uint4*)(xtl + addr * 16 + 8) = make_uint4(dl[4], dl[5], dl[6], dl[7]);
    } else {  // W fragment-packed: wrp[t][ocg][lane][j]
        int idx = (blk - 784 - 197) * 256 + threadIdx.x;
        if (idx >= 13 * 4 * 64 * 8) return;
        int j = idx & 7;
        int lane = (idx >> 3) & 63;
        int ocg = (idx >> 9) & 3;
        int t = idx >> 11;
        int k = (lane >> 4) * 8 + j;
        int s = k >> 4, c = k & 15;
        int oc = 16 * ocg + (lane & 15);
        int tap = 2 * t + s;
        float v = (tap < 25) ? W[oc * 400 + c * 25 + tap] : 0.f;
        uint16_t h = f2bf(v);
        wrh[idx] = h;
        wrl[idx] = f2bf(v - bf2f(h));
    }
}

// ---- Kernel 1: conv MFMA (packed-A, coalesced) + FUSED inhibition epilogue ----
__global__ __launch_bounds__(256) void conv_inhib_kernel(const uint16_t* __restrict__ xth,
                                                         const uint16_t* __restrict__ xtl,
                                                         const uint16_t* __restrict__ wrh,
                                                         const uint16_t* __restrict__ wrl,
                                                         float* __restrict__ out,
                                                         uint16_t* __restrict__ yb) {
    const int lane = threadIdx.x & 63;
    const int w = threadIdx.x >> 6;   // oc-group: rows 16w..16w+15
    const int l15 = lane & 15;
    const int quad = lane >> 4;
    const int P0 = blockIdx.x * 64;
    const int c0 = (quad & 1) * 8;
    const int sq = quad >> 1;

    floatx4 acc[4];
#pragma unroll
    for (int g = 0; g < 4; g++) acc[g] = (floatx4){0.f, 0.f, 0.f, 0.f};

#pragma unroll
    for (int t = 0; t < 13; t++) {
        short8 ah = *(const short8*)(wrh + ((t * 4 + w) * 64 + lane) * 8);
        short8 al = *(const short8*)(wrl + ((t * 4 + w) * 64 + lane) * 8);
        const int tap0 = 2 * t, tap1 = 2 * t + 1;
        const int o0 = (tap0 / 5) * 224 + (tap0 % 5);
        const int o1 = (tap1 <= 24) ? (tap1 / 5) * 224 + (tap1 % 5) : 0;
        const int off = sq ? o1 : o0;
#pragma unroll
        for (int g = 0; g < 4; g++) {
            int P = P0 + 16 * g + l15;
            short8 bh = *(const short8*)(xth + (P + off) * 16 + c0);
            short8 bl = *(const short8*)(xtl + (P + off) * 16 + c0);
            acc[g] = __builtin_amdgcn_mfma_f32_16x16x32_bf16(ah, bh, acc[g], 0, 0, 0);
            acc[g] = __builtin_amdgcn_mfma_f32_16x16x32_bf16(ah, bl, acc[g], 0, 0, 0);
            acc[g] = __builtin_amdgcn_mfma_f32_16x16x32_bf16(al, bh, acc[g], 0, 0, 0);
        }
    }

    __shared__ float wmax[4][64];
    float pmax[4];
#pragma unroll
    for (int g = 0; g < 4; g++) {
        float mx = fmaxf(fmaxf(acc[g][0], acc[g][1]), fmaxf(acc[g][2], acc[g][3]));
        mx = fmaxf(mx, 0.f);
        mx = fmaxf(mx, __shfl_xor(mx, 16));
        mx = fmaxf(mx, __shfl_xor(mx, 32));
        pmax[g] = mx;
    }
    if (quad == 0) {
#pragma unroll
        for (int g = 0; g < 4; g++) wmax[w][g * 16 + l15] = pmax[g];
    }
    __syncthreads();

#pragma unroll
    for (int g = 0; g < 4; g++) {
        int P = P0 + 16 * g + l15;
        int i = P / 224;
        int j = P - i * 224;
        bool valid = j < NH;
        float mx = fmaxf(fmaxf(wmax[0][g * 16 + l15], wmax[1][g * 16 + l15]),
                         fmaxf(wmax[2][g * 16 + l15], wmax[3][g * 16 + l15]));
        float inv = 1.f / (mx + 1e-9f);
#pragma unroll
        for (int r = 0; r < 4; r++) {
            float tv = fmaxf(acc[g][r], 0.f) * inv;
            float t2 = tv * tv;
            tv = t2 * t2 * tv;
            if (valid) {
                int oc = 16 * w + quad * 4 + r;
                out[oc * OUT_PLANE + i * NH + j] = tv;
                yb[oc * KP2 + P] = f2bf(tv);
            }
        }
    }
}

// ---- Kernel 2: LDS-staged GEMM y^T @ [xf|y|1], compact-xc B with funnel-shift staging ----
__global__ __launch_bounds__(256) void gemm_kernel(const uint16_t* __restrict__ yb,
                                                   const uint16_t* __restrict__ xc,
                                                   const uint16_t* __restrict__ ones,
                                                   float* __restrict__ Mpart) {
    __shared__ uint16_t As[2][64 * 40];
    __shared__ uint16_t Bs[2][64 * 40];
    const int tid = threadIdx.x;
    const int lane = tid & 63;
    const int w = tid >> 6;
    const int l15 = lane & 15;
    const int quad = lane >> 4;
    const int kg = quad * 8;
    const int b = blockIdx.x;
    const int xcd = b & 7;
    const int t8 = b >> 3;
    const int ntile = t8 & 7;
    const int chunk = xcd + 8 * (t8 >> 3);
    const int k0 = chunk * CK;

    const int sr = tid >> 2;
    const int sseg = (tid & 3) * 8;
    const uint16_t* pa = yb + sr * KP2 + k0 + sseg;

    int n_g = ntile * 64 + sr;
    const uint16_t* pbase;
    int fidx = 0, fsh = 0;  // funnel params (0,0 = identity for aligned columns)
    if (n_g < 400) {
        int c = n_g / 25;
        int r = n_g - 25 * c;
        int ki = r / 5;
        int kj = r - 5 * ki;
        pbase = xc + c * XCH + ki * 224;  // aligned base; data starts kj elements in
        fidx = kj >> 1;
        fsh = (kj & 1) * 16;
    } else if (n_g < 464) {
        pbase = yb + (n_g - 400) * KP2;
    } else if (n_g == 464) {
        pbase = ones;
    } else {
        pbase = yb;  // dead column
    }
    const uint16_t* pb = pbase + k0 + sseg;

    floatx4 acc[4];
#pragma unroll
    for (int i = 0; i < 4; i++) acc[i] = (floatx4){0.f, 0.f, 0.f, 0.f};

    uint4 ra = *(const uint4*)pa;
    uint4 rb = *(const uint4*)pb;
    uint2 rbx = *(const uint2*)(pb + 8);

    for (int s = 0; s < 25; s++) {
        const int p = s & 1;
        *(uint4*)&As[p][sr * 40 + sseg] = ra;
        {   // funnel-extract 8 bf16 starting at element offset kj within [pb, pb+12)
            uint32_t dw[7];
            *(uint4*)dw = rb;
            *(uint2*)(dw + 4) = rbx;
            dw[6] = 0u;
            uint32_t bo[4];
#pragma unroll
            for (int t = 0; t < 4; t++)
                bo[t] = (uint32_t)((((uint64_t)dw[fidx + t + 1] << 32) | dw[fidx + t]) >> fsh);
            *(uint4*)&Bs[p][sr * 40 + sseg] = *(uint4*)bo;
        }
        __syncthreads();
        if (s + 1 < 25) {
            pa += 32;
            pb += 32;
            ra = *(const uint4*)pa;
            rb = *(const uint4*)pb;
            rbx = *(const uint2*)(pb + 8);
        }
        short8 af = *(const short8*)&As[p][(16 * w + l15) * 40 + kg];
#pragma unroll
        for (int ng = 0; ng < 4; ng++) {
            short8 bf = *(const short8*)&Bs[p][(16 * ng + l15) * 40 + kg];
            acc[ng] = __builtin_amdgcn_mfma_f32_16x16x32_bf16(af, bf, acc[ng], 0, 0, 0);
        }
        __syncthreads();
    }

    float* dst = Mpart + chunk * PSTRIDE;
#pragma unroll
    for (int ng = 0; ng < 4; ng++) {
        int col = ntile * 64 + ng * 16 + l15;
        if (col < 465) {
#pragma unroll
            for (int r = 0; r < 4; r++)
                dst[(16 * w + quad * 4 + r) * 512 + col] = acc[ng][r];
        }
    }
}

// ---- Kernel 3: FUSED reduce + finalize: Mpart -> Wout, expout ----
__global__ __launch_bounds__(256) void finalize_w_kernel(const float* __restrict__ W,
                                                         const float* __restrict__ Mpart,
                                                         const float* __restrict__ exp_avg,
                                                         float* __restrict__ Wout,
                                                         float* __restrict__ expout) {
    __shared__ float gfps[OUT_CH];
    __shared__ float ytys[2][OUT_CH];
    const int tid = threadIdx.x;
    const int bid = blockIdx.x;
    const int first_o = (bid * 256) / 400;

    if (tid < OUT_CH) {  // colsum -> exp_new -> gfp
        int o = tid;
        float cs = 0.f;
#pragma unroll 8
        for (int ch = 0; ch < NCHUNK; ch++) cs += Mpart[ch * PSTRIDE + o * 512 + 464];
        float e = GAMMA_F * exp_avg[o] + ONE_MINUS_GAMMA * (cs / (float)NB_TILES);
        float s = e;
        for (int off = 32; off; off >>= 1) s += __shfl_down(s, off);
        s = __shfl(s, 0);
        float A = e / (s / (float)OUT_CH);
        gfps[o] = EPS_F * tanhf(-EPS_F * (A - 1.f)) + 1.f;
        if (bid == 0) expout[o] = e;
    }
    if (tid >= 128) {  // the <=2 yty rows this block needs
        int t = tid - 128;
        int orow = first_o + (t >> 6);
        int k = t & 63;
        float s = 0.f;
        if (orow < OUT_CH) {
#pragma unroll 8
            for (int ch = 0; ch < NCHUNK; ch++) s += Mpart[ch * PSTRIDE + orow * 512 + 400 + k];
        }
        ytys[t >> 6][k] = s;
    }
    __syncthreads();

    int idx = bid * 256 + tid;
    int o = idx / 400;
    int q = idx - o * 400;
    float Mv = 0.f;
#pragma unroll 8
    for (int ch = 0; ch < NCHUNK; ch++) Mv += Mpart[ch * PSTRIDE + o * 512 + q];
    const float* yrow = ytys[o - first_o];
    float dot = 0.f;
#pragma unroll 8
    for (int k = 0; k < OUT_CH; k++) dot = fmaf(yrow[k], W[k * 400 + q], dot);
    float wv = W[idx] + LR_OVER_NB * (Mv - dot);
    wv = fmaxf(wv, 0.f);
    float gp = gfps[o];
    float pos = (wv > 0.f ? wv : 0.f) * gp;
    float neg = (wv < 0.f ? wv : 0.f) / gp;
    Wout[idx] = pos + neg;
}

extern "C" void kernel_launch(void* const* d_in, const int* in_sizes, int n_in,
                              void* d_out, int out_size, void* d_ws, size_t ws_size,
                              hipStream_t stream) {
    const float* x = (const float*)d_in[0];
    const float* W = (const float*)d_in[1];
    const float* exp_avg = (const float*)d_in[2];
    float* out = (float*)d_out;

    float* wsf = (float*)d_ws;
    float* Mpart = wsf + 29760;                 // 64*32768 floats
    // conv-side buffers overlaid on Mpart (dead until gemm writes it)
    uint16_t* xth = (uint16_t*)Mpart;           // 50304*16
    uint16_t* xtl = xth + XTROWS * 16;          // 50304*16
    uint16_t* wrh = xtl + XTROWS * 16;          // 26624
    uint16_t* wrl = wrh + 26624;                // 26624
    uint16_t* ybf = (uint16_t*)(wsf + 29760 + NCHUNK * PSTRIDE);  // 64*51200 bf16
    uint16_t* xcb = ybf + OUT_CH * KP2;                            // 16*50176 + 2048 bf16
    uint16_t* ones = xcb + 16 * XCH + XCPAD;                       // 51264 bf16

    float* Wout = out + OUT_CH * OUT_PLANE;
    float* expout = Wout + OUT_CH * IN_CH * KER * KER;

    prep_kernel<<<784 + 197 + 104, 256, 0, stream>>>(x, xcb, ybf, ones, xth, xtl, W, wrh, wrl);
    conv_inhib_kernel<<<770, 256, 0, stream>>>(xth, xtl, wrh, wrl, out, ybf);
    gemm_kernel<<<512, 256, 0, stream>>>(ybf, xcb, ones, Mpart);
    finalize_w_kernel<<<100, 256, 0, stream>>>(W, Mpart, exp_avg, Wout, expout);
}

// Round 18
// 118.459 us; speedup vs baseline: 1.1402x; 1.0479x over previous
//
#include <hip/hip_runtime.h>
#include <stdint.h>

#define IN_SIZE 224
#define KER 5
#define IN_CH 16
#define OUT_CH 64
#define NH 220
#define NB_TILES (NH * NH)       // 48400
#define XCH (IN_SIZE * IN_SIZE)  // 50176
#define OUT_PLANE NB_TILES
#define KP2 51200                // padded K for gemm
#define XS 52224                 // per-plane stride in shifted-x copies
#define XTROWS 50304             // xT rows (XCH + pad for tap overhang)
#define LR_OVER_NB ((float)(0.005 / 48400.0))
#define GAMMA_F 0.99f
#define ONE_MINUS_GAMMA 0.01f
#define EPS_F 0.01f

#define NCHUNK 64
#define CK 800                   // 25 steps of BK=32
#define PSTRIDE (64 * 512)

typedef __attribute__((ext_vector_type(8))) short short8;
typedef __attribute__((ext_vector_type(4))) float floatx4;

__device__ inline uint16_t f2bf(float f) {
    uint32_t u = __float_as_uint(f);
    return (uint16_t)((u + 0x7FFFu + ((u >> 16) & 1u)) >> 16);
}
__device__ inline float bf2f(uint16_t h) { return __uint_as_float((uint32_t)h << 16); }

// ---- Kernel 0: prepA: xT hi/lo + W fragment-packed repack (conv's inputs only) ----
__global__ __launch_bounds__(256) void prepa_kernel(const float* __restrict__ x,
                                                    uint16_t* __restrict__ xth,
                                                    uint16_t* __restrict__ xtl,
                                                    const float* __restrict__ W,
                                                    uint16_t* __restrict__ wrh,
                                                    uint16_t* __restrict__ wrl) {
    int blk = blockIdx.x;
    if (blk < 197) {  // xT hi/lo
        int addr = blk * 256 + threadIdx.x;
        if (addr >= XTROWS) return;
        uint32_t dh[8], dl[8];
        if (addr < XCH) {
#pragma unroll
            for (int q = 0; q < 8; q++) {
                float v0 = x[(2 * q) * XCH + addr];
                float v1 = x[(2 * q + 1) * XCH + addr];
                uint16_t h0 = f2bf(v0), h1 = f2bf(v1);
                uint16_t l0 = f2bf(v0 - bf2f(h0)), l1 = f2bf(v1 - bf2f(h1));
                dh[q] = (uint32_t)h0 | ((uint32_t)h1 << 16);
                dl[q] = (uint32_t)l0 | ((uint32_t)l1 << 16);
            }
        } else {
#pragma unroll
            for (int q = 0; q < 8; q++) { dh[q] = 0u; dl[q] = 0u; }
        }
        *(uint4*)(xth + addr * 16) = make_uint4(dh[0], dh[1], dh[2], dh[3]);
        *(uint4*)(xth + addr * 16 + 8) = make_uint4(dh[4], dh[5], dh[6], dh[7]);
        *(uint4*)(xtl + addr * 16) = make_uint4(dl[0], dl[1], dl[2], dl[3]);
        *(uint4*)(xtl + addr * 16 + 8) = make_uint4(dl[4], dl[5], dl[6], dl[7]);
    } else {  // W fragment-packed: wrp[t][ocg][lane][j]
        int idx = (blk - 197) * 256 + threadIdx.x;
        if (idx >= 13 * 4 * 64 * 8) return;
        int j = idx & 7;
        int lane = (idx >> 3) & 63;
        int ocg = (idx >> 9) & 3;
        int t = idx >> 11;
        int k = (lane >> 4) * 8 + j;
        int s = k >> 4, c = k & 15;
        int oc = 16 * ocg + (lane & 15);
        int tap = 2 * t + s;
        float v = (tap < 25) ? W[oc * 400 + c * 25 + tap] : 0.f;
        uint16_t h = f2bf(v);
        wrh[idx] = h;
        wrl[idx] = f2bf(v - bf2f(h));
    }
}

// ---- Kernel 1: conv MFMA + inhibition, FUSED with prepB (shifted x copies/pads/ones) ----
// blocks 0..769: conv; blocks 770..4849: prepB (independent memory work, overlaps conv)
__global__ __launch_bounds__(256) void conv_prep_kernel(const uint16_t* __restrict__ xth,
                                                        const uint16_t* __restrict__ xtl,
                                                        const uint16_t* __restrict__ wrh,
                                                        const uint16_t* __restrict__ wrl,
                                                        float* __restrict__ out,
                                                        uint16_t* __restrict__ yb,
                                                        const float* __restrict__ x,
                                                        uint16_t* __restrict__ xs,
                                                        uint16_t* __restrict__ ones) {
    if (blockIdx.x >= 770) {  // ---- prepB ----
        int t = (blockIdx.x - 770) * 256 + threadIdx.x;
        const int perq = XS / 4;  // 13056
        if (t < 5 * 16 * perq) {
            int kj = t / (16 * perq);
            int rem = t - kj * (16 * perq);
            int c = rem / perq;
            int q = (rem - c * perq) * 4;
            int base = c * XCH;
            ushort4 o;
            int i0 = q + kj;     o.x = f2bf(x[base + (i0 < XCH ? i0 : XCH - 1)]);
            int i1 = q + kj + 1; o.y = f2bf(x[base + (i1 < XCH ? i1 : XCH - 1)]);
            int i2 = q + kj + 2; o.z = f2bf(x[base + (i2 < XCH ? i2 : XCH - 1)]);
            int i3 = q + kj + 3; o.w = f2bf(x[base + (i3 < XCH ? i3 : XCH - 1)]);
            *(ushort4*)(xs + (kj * 16 + c) * XS + q) = o;
        }
        ushort4 z = {0, 0, 0, 0};
        if (t < 64 * 480) {  // zero yb K-tail [49280,51200)
            int r = t / 480, q = (t - r * 480) * 4;
            *(ushort4*)(yb + r * KP2 + 49280 + q) = z;
        }
        if (t < 64 * 220) {  // zero yb j-pad cols 220..223
            int o = t / 220, i = t - o * 220;
            *(ushort4*)(yb + o * KP2 + i * 224 + 220) = z;
        }
        if (t < 12816) {  // bf16 ones (51264 entries)
            ushort4 o1 = {0x3F80, 0x3F80, 0x3F80, 0x3F80};
            ((ushort4*)ones)[t] = o1;
        }
        return;
    }

    // ---- conv + inhibition (identical to R15) ----
    const int lane = threadIdx.x & 63;
    const int w = threadIdx.x >> 6;
    const int l15 = lane & 15;
    const int quad = lane >> 4;
    const int P0 = blockIdx.x * 64;
    const int c0 = (quad & 1) * 8;
    const int sq = quad >> 1;

    floatx4 acc[4];
#pragma unroll
    for (int g = 0; g < 4; g++) acc[g] = (floatx4){0.f, 0.f, 0.f, 0.f};

#pragma unroll
    for (int t = 0; t < 13; t++) {
        short8 ah = *(const short8*)(wrh + ((t * 4 + w) * 64 + lane) * 8);
        short8 al = *(const short8*)(wrl + ((t * 4 + w) * 64 + lane) * 8);
        const int tap0 = 2 * t, tap1 = 2 * t + 1;
        const int o0 = (tap0 / 5) * 224 + (tap0 % 5);
        const int o1 = (tap1 <= 24) ? (tap1 / 5) * 224 + (tap1 % 5) : 0;
        const int off = sq ? o1 : o0;
#pragma unroll
        for (int g = 0; g < 4; g++) {
            int P = P0 + 16 * g + l15;
            short8 bh = *(const short8*)(xth + (P + off) * 16 + c0);
            short8 bl = *(const short8*)(xtl + (P + off) * 16 + c0);
            acc[g] = __builtin_amdgcn_mfma_f32_16x16x32_bf16(ah, bh, acc[g], 0, 0, 0);
            acc[g] = __builtin_amdgcn_mfma_f32_16x16x32_bf16(ah, bl, acc[g], 0, 0, 0);
            acc[g] = __builtin_amdgcn_mfma_f32_16x16x32_bf16(al, bh, acc[g], 0, 0, 0);
        }
    }

    __shared__ float wmax[4][64];
    float pmax[4];
#pragma unroll
    for (int g = 0; g < 4; g++) {
        float mx = fmaxf(fmaxf(acc[g][0], acc[g][1]), fmaxf(acc[g][2], acc[g][3]));
        mx = fmaxf(mx, 0.f);
        mx = fmaxf(mx, __shfl_xor(mx, 16));
        mx = fmaxf(mx, __shfl_xor(mx, 32));
        pmax[g] = mx;
    }
    if (quad == 0) {
#pragma unroll
        for (int g = 0; g < 4; g++) wmax[w][g * 16 + l15] = pmax[g];
    }
    __syncthreads();

#pragma unroll
    for (int g = 0; g < 4; g++) {
        int P = P0 + 16 * g + l15;
        int i = P / 224;
        int j = P - i * 224;
        bool valid = j < NH;
        float mx = fmaxf(fmaxf(wmax[0][g * 16 + l15], wmax[1][g * 16 + l15]),
                         fmaxf(wmax[2][g * 16 + l15], wmax[3][g * 16 + l15]));
        float inv = 1.f / (mx + 1e-9f);
#pragma unroll
        for (int r = 0; r < 4; r++) {
            float tv = fmaxf(acc[g][r], 0.f) * inv;
            float t2 = tv * tv;
            tv = t2 * t2 * tv;
            if (valid) {
                int oc = 16 * w + quad * 4 + r;
                out[oc * OUT_PLANE + i * NH + j] = tv;
                yb[oc * KP2 + P] = f2bf(tv);
            }
        }
    }
}

// ---- Kernel 2: LDS-staged GEMM y^T @ [xf|y|1] (R15/R12 config, shifted-copy B) ----
__global__ __launch_bounds__(256) void gemm_kernel(const uint16_t* __restrict__ yb,
                                                   const uint16_t* __restrict__ xs,
                                                   const uint16_t* __restrict__ ones,
                                                   float* __restrict__ Mpart) {
    __shared__ uint16_t As[2][64 * 40];
    __shared__ uint16_t Bs[2][64 * 40];
    const int tid = threadIdx.x;
    const int lane = tid & 63;
    const int w = tid >> 6;
    const int l15 = lane & 15;
    const int quad = lane >> 4;
    const int kg = quad * 8;
    const int b = blockIdx.x;
    const int xcd = b & 7;
    const int t8 = b >> 3;
    const int ntile = t8 & 7;
    const int chunk = xcd + 8 * (t8 >> 3);
    const int k0 = chunk * CK;

    const int sr = tid >> 2;
    const int sseg = (tid & 3) * 8;
    const uint16_t* pa = yb + sr * KP2 + k0 + sseg;

    int n_g = ntile * 64 + sr;
    const uint16_t* pbase;
    if (n_g < 400) {
        int c = n_g / 25;
        int r = n_g - 25 * c;
        int ki = r / 5;
        int kj = r - 5 * ki;
        pbase = xs + (kj * 16 + c) * XS + ki * 224;
    } else if (n_g < 464) {
        pbase = yb + (n_g - 400) * KP2;
    } else if (n_g == 464) {
        pbase = ones;
    } else {
        pbase = yb;  // dead column
    }
    const uint16_t* pb = pbase + k0 + sseg;

    floatx4 acc[4];
#pragma unroll
    for (int i = 0; i < 4; i++) acc[i] = (floatx4){0.f, 0.f, 0.f, 0.f};

    uint4 ra = *(const uint4*)pa;
    uint4 rb = *(const uint4*)pb;

    for (int s = 0; s < 25; s++) {
        const int p = s & 1;
        *(uint4*)&As[p][sr * 40 + sseg] = ra;
        *(uint4*)&Bs[p][sr * 40 + sseg] = rb;
        __syncthreads();
        if (s + 1 < 25) {
            pa += 32;
            pb += 32;
            ra = *(const uint4*)pa;
            rb = *(const uint4*)pb;
        }
        short8 af = *(const short8*)&As[p][(16 * w + l15) * 40 + kg];
#pragma unroll
        for (int ng = 0; ng < 4; ng++) {
            short8 bf = *(const short8*)&Bs[p][(16 * ng + l15) * 40 + kg];
            acc[ng] = __builtin_amdgcn_mfma_f32_16x16x32_bf16(af, bf, acc[ng], 0, 0, 0);
        }
        __syncthreads();
    }

    float* dst = Mpart + chunk * PSTRIDE;
#pragma unroll
    for (int ng = 0; ng < 4; ng++) {
        int col = ntile * 64 + ng * 16 + l15;
        if (col < 465) {
#pragma unroll
            for (int r = 0; r < 4; r++)
                dst[(16 * w + quad * 4 + r) * 512 + col] = acc[ng][r];
        }
    }
}

// ---- Kernel 3: FUSED reduce + finalize: Mpart -> Wout, expout ----
__global__ __launch_bounds__(256) void finalize_w_kernel(const float* __restrict__ W,
                                                         const float* __restrict__ Mpart,
                                                         const float* __restrict__ exp_avg,
                                                         float* __restrict__ Wout,
                                                         float* __restrict__ expout) {
    __shared__ float gfps[OUT_CH];
    __shared__ float ytys[2][OUT_CH];
    const int tid = threadIdx.x;
    const int bid = blockIdx.x;
    const int first_o = (bid * 256) / 400;

    if (tid < OUT_CH) {  // colsum -> exp_new -> gfp
        int o = tid;
        float cs = 0.f;
#pragma unroll 8
        for (int ch = 0; ch < NCHUNK; ch++) cs += Mpart[ch * PSTRIDE + o * 512 + 464];
        float e = GAMMA_F * exp_avg[o] + ONE_MINUS_GAMMA * (cs / (float)NB_TILES);
        float s = e;
        for (int off = 32; off; off >>= 1) s += __shfl_down(s, off);
        s = __shfl(s, 0);
        float A = e / (s / (float)OUT_CH);
        gfps[o] = EPS_F * tanhf(-EPS_F * (A - 1.f)) + 1.f;
        if (bid == 0) expout[o] = e;
    }
    if (tid >= 128) {  // the <=2 yty rows this block needs
        int t = tid - 128;
        int orow = first_o + (t >> 6);
        int k = t & 63;
        float s = 0.f;
        if (orow < OUT_CH) {
#pragma unroll 8
            for (int ch = 0; ch < NCHUNK; ch++) s += Mpart[ch * PSTRIDE + orow * 512 + 400 + k];
        }
        ytys[t >> 6][k] = s;
    }
    __syncthreads();

    int idx = bid * 256 + tid;
    int o = idx / 400;
    int q = idx - o * 400;
    float Mv = 0.f;
#pragma unroll 8
    for (int ch = 0; ch < NCHUNK; ch++) Mv += Mpart[ch * PSTRIDE + o * 512 + q];
    const float* yrow = ytys[o - first_o];
    float dot = 0.f;
#pragma unroll 8
    for (int k = 0; k < OUT_CH; k++) dot = fmaf(yrow[k], W[k * 400 + q], dot);
    float wv = W[idx] + LR_OVER_NB * (Mv - dot);
    wv = fmaxf(wv, 0.f);
    float gp = gfps[o];
    float pos = (wv > 0.f ? wv : 0.f) * gp;
    float neg = (wv < 0.f ? wv : 0.f) / gp;
    Wout[idx] = pos + neg;
}

extern "C" void kernel_launch(void* const* d_in, const int* in_sizes, int n_in,
                              void* d_out, int out_size, void* d_ws, size_t ws_size,
                              hipStream_t stream) {
    const float* x = (const float*)d_in[0];
    const float* W = (const float*)d_in[1];
    const float* exp_avg = (const float*)d_in[2];
    float* out = (float*)d_out;

    float* wsf = (float*)d_ws;
    float* Mpart = wsf + 29760;                 // 64*32768 floats
    // conv-side buffers overlaid on Mpart (dead until gemm writes it)
    uint16_t* xth = (uint16_t*)Mpart;           // 50304*16
    uint16_t* xtl = xth + XTROWS * 16;          // 50304*16
    uint16_t* wrh = xtl + XTROWS * 16;          // 26624
    uint16_t* wrl = wrh + 26624;                // 26624
    uint16_t* ybf = (uint16_t*)(wsf + 29760 + NCHUNK * PSTRIDE);  // 64*51200 bf16
    uint16_t* xsb = ybf + OUT_CH * KP2;                            // 5*16*52224 bf16
    uint16_t* ones = xsb + 5 * 16 * XS;                            // 51264 bf16

    float* Wout = out + OUT_CH * OUT_PLANE;
    float* expout = Wout + OUT_CH * IN_CH * KER * KER;

    prepa_kernel<<<301, 256, 0, stream>>>(x, xth, xtl, W, wrh, wrl);
    conv_prep_kernel<<<770 + 4080, 256, 0, stream>>>(xth, xtl, wrh, wrl, out, ybf, x, xsb, ones);
    gemm_kernel<<<512, 256, 0, stream>>>(ybf, xsb, ones, Mpart);
    finalize_w_kernel<<<100, 256, 0, stream>>>(W, Mpart, exp_avg, Wout, expout);
}

// Round 19
// 109.613 us; speedup vs baseline: 1.2322x; 1.0807x over previous
//
#include <hip/hip_runtime.h>
#include <stdint.h>

#define IN_SIZE 224
#define KER 5
#define IN_CH 16
#define OUT_CH 64
#define NH 220
#define NB_TILES (NH * NH)       // 48400
#define XCH (IN_SIZE * IN_SIZE)  // 50176
#define OUT_PLANE NB_TILES
#define KP2 51200                // padded K for gemm
#define XS 52224                 // per-plane stride in shifted-x copies
#define XTROWS 50304             // xT rows (XCH + pad for tap overhang)
#define LR_OVER_NB ((float)(0.005 / 48400.0))
#define GAMMA_F 0.99f
#define ONE_MINUS_GAMMA 0.01f
#define EPS_F 0.01f

#define NCHUNK 64
#define CK 800                   // 25 steps of BK=32
#define PSTRIDE (64 * 512)

typedef __attribute__((ext_vector_type(8))) short short8;
typedef __attribute__((ext_vector_type(4))) float floatx4;

__device__ inline uint16_t f2bf(float f) {
    uint32_t u = __float_as_uint(f);
    return (uint16_t)((u + 0x7FFFu + ((u >> 16) & 1u)) >> 16);
}
__device__ inline float bf2f(uint16_t h) { return __uint_as_float((uint32_t)h << 16); }

// ---- Kernel 0: prepA: xT hi/lo + W fragment-packed repack (conv's inputs only) ----
__global__ __launch_bounds__(256) void prepa_kernel(const float* __restrict__ x,
                                                    uint16_t* __restrict__ xth,
                                                    uint16_t* __restrict__ xtl,
                                                    const float* __restrict__ W,
                                                    uint16_t* __restrict__ wrh,
                                                    uint16_t* __restrict__ wrl) {
    int blk = blockIdx.x;
    if (blk < 197) {  // xT hi/lo
        int addr = blk * 256 + threadIdx.x;
        if (addr >= XTROWS) return;
        uint32_t dh[8], dl[8];
        if (addr < XCH) {
#pragma unroll
            for (int q = 0; q < 8; q++) {
                float v0 = x[(2 * q) * XCH + addr];
                float v1 = x[(2 * q + 1) * XCH + addr];
                uint16_t h0 = f2bf(v0), h1 = f2bf(v1);
                uint16_t l0 = f2bf(v0 - bf2f(h0)), l1 = f2bf(v1 - bf2f(h1));
                dh[q] = (uint32_t)h0 | ((uint32_t)h1 << 16);
                dl[q] = (uint32_t)l0 | ((uint32_t)l1 << 16);
            }
        } else {
#pragma unroll
            for (int q = 0; q < 8; q++) { dh[q] = 0u; dl[q] = 0u; }
        }
        *(uint4*)(xth + addr * 16) = make_uint4(dh[0], dh[1], dh[2], dh[3]);
        *(uint4*)(xth + addr * 16 + 8) = make_uint4(dh[4], dh[5], dh[6], dh[7]);
        *(uint4*)(xtl + addr * 16) = make_uint4(dl[0], dl[1], dl[2], dl[3]);
        *(uint4*)(xtl + addr * 16 + 8) = make_uint4(dl[4], dl[5], dl[6], dl[7]);
    } else {  // W fragment-packed: wrp[t][ocg][lane][j]
        int idx = (blk - 197) * 256 + threadIdx.x;
        if (idx >= 13 * 4 * 64 * 8) return;
        int j = idx & 7;
        int lane = (idx >> 3) & 63;
        int ocg = (idx >> 9) & 3;
        int t = idx >> 11;
        int k = (lane >> 4) * 8 + j;
        int s = k >> 4, c = k & 15;
        int oc = 16 * ocg + (lane & 15);
        int tap = 2 * t + s;
        float v = (tap < 25) ? W[oc * 400 + c * 25 + tap] : 0.f;
        uint16_t h = f2bf(v);
        wrh[idx] = h;
        wrl[idx] = f2bf(v - bf2f(h));
    }
}

// ---- Kernel 1: conv MFMA (B via LDS-staged 5-strip window) + inhibition; prepB fused ----
// blocks 0..769: conv; blocks 770..4849: prepB (independent memory work, overlaps conv)
__global__ __launch_bounds__(256) void conv_prep_kernel(const uint16_t* __restrict__ xth,
                                                        const uint16_t* __restrict__ xtl,
                                                        const uint16_t* __restrict__ wrh,
                                                        const uint16_t* __restrict__ wrl,
                                                        float* __restrict__ out,
                                                        uint16_t* __restrict__ yb,
                                                        const float* __restrict__ x,
                                                        uint16_t* __restrict__ xs,
                                                        uint16_t* __restrict__ ones) {
    if (blockIdx.x >= 770) {  // ---- prepB ----
        int t = (blockIdx.x - 770) * 256 + threadIdx.x;
        const int perq = XS / 4;  // 13056
        if (t < 5 * 16 * perq) {
            int kj = t / (16 * perq);
            int rem = t - kj * (16 * perq);
            int c = rem / perq;
            int q = (rem - c * perq) * 4;
            int base = c * XCH;
            ushort4 o;
            int i0 = q + kj;     o.x = f2bf(x[base + (i0 < XCH ? i0 : XCH - 1)]);
            int i1 = q + kj + 1; o.y = f2bf(x[base + (i1 < XCH ? i1 : XCH - 1)]);
            int i2 = q + kj + 2; o.z = f2bf(x[base + (i2 < XCH ? i2 : XCH - 1)]);
            int i3 = q + kj + 3; o.w = f2bf(x[base + (i3 < XCH ? i3 : XCH - 1)]);
            *(ushort4*)(xs + (kj * 16 + c) * XS + q) = o;
        }
        ushort4 z = {0, 0, 0, 0};
        if (t < 64 * 480) {  // zero yb K-tail [49280,51200)
            int r = t / 480, q = (t - r * 480) * 4;
            *(ushort4*)(yb + r * KP2 + 49280 + q) = z;
        }
        if (t < 64 * 220) {  // zero yb j-pad cols 220..223
            int o = t / 220, i = t - o * 220;
            *(ushort4*)(yb + o * KP2 + i * 224 + 220) = z;
        }
        if (t < 12816) {  // bf16 ones (51264 entries)
            ushort4 o1 = {0x3F80, 0x3F80, 0x3F80, 0x3F80};
            ((ushort4*)ones)[t] = o1;
        }
        return;
    }

    // ---- conv: stage the block's B-window (5 strips x 68 rows x 16ch, hi+lo) in LDS ----
    const int lane = threadIdx.x & 63;
    const int w = threadIdx.x >> 6;
    const int l15 = lane & 15;
    const int quad = lane >> 4;
    const int P0 = blockIdx.x * 64;
    const int c0 = (quad & 1) * 8;
    const int sq = quad >> 1;

    __shared__ uint16_t bsh[5 * 68 * 16];  // 10.9 KB
    __shared__ uint16_t bsl[5 * 68 * 16];  // 10.9 KB
    for (int u = threadIdx.x; u < 680; u += 256) {
        int row = u >> 1;            // 0..339
        int half = (u & 1) * 8;      // elem offset 0 / 8
        int strip = row / 68;
        int rr = row - strip * 68;
        int grow = P0 + strip * 224 + rr;  // <= 50179 < XTROWS
        *(uint4*)(bsh + row * 16 + half) = *(const uint4*)(xth + grow * 16 + half);
        *(uint4*)(bsl + row * 16 + half) = *(const uint4*)(xtl + grow * 16 + half);
    }
    __syncthreads();

    floatx4 acc[4];
#pragma unroll
    for (int g = 0; g < 4; g++) acc[g] = (floatx4){0.f, 0.f, 0.f, 0.f};

#pragma unroll
    for (int t = 0; t < 13; t++) {
        short8 ah = *(const short8*)(wrh + ((t * 4 + w) * 64 + lane) * 8);
        short8 al = *(const short8*)(wrl + ((t * 4 + w) * 64 + lane) * 8);
        const int tap0 = 2 * t, tap1 = 2 * t + 1;
        const int ki0 = tap0 / 5, kj0 = tap0 % 5;
        const int ki1 = (tap1 <= 24) ? tap1 / 5 : 0;
        const int kj1 = (tap1 <= 24) ? tap1 % 5 : 0;
        const int strip = sq ? ki1 : ki0;
        const int kjv = sq ? kj1 : kj0;
#pragma unroll
        for (int g = 0; g < 4; g++) {
            int lrow = strip * 68 + 16 * g + l15 + kjv;
            short8 bh = *(const short8*)(bsh + lrow * 16 + c0);
            short8 bl = *(const short8*)(bsl + lrow * 16 + c0);
            acc[g] = __builtin_amdgcn_mfma_f32_16x16x32_bf16(ah, bh, acc[g], 0, 0, 0);
            acc[g] = __builtin_amdgcn_mfma_f32_16x16x32_bf16(ah, bl, acc[g], 0, 0, 0);
            acc[g] = __builtin_amdgcn_mfma_f32_16x16x32_bf16(al, bh, acc[g], 0, 0, 0);
        }
    }

    __shared__ float wmax[4][64];
    float pmax[4];
#pragma unroll
    for (int g = 0; g < 4; g++) {
        float mx = fmaxf(fmaxf(acc[g][0], acc[g][1]), fmaxf(acc[g][2], acc[g][3]));
        mx = fmaxf(mx, 0.f);
        mx = fmaxf(mx, __shfl_xor(mx, 16));
        mx = fmaxf(mx, __shfl_xor(mx, 32));
        pmax[g] = mx;
    }
    if (quad == 0) {
#pragma unroll
        for (int g = 0; g < 4; g++) wmax[w][g * 16 + l15] = pmax[g];
    }
    __syncthreads();

#pragma unroll
    for (int g = 0; g < 4; g++) {
        int P = P0 + 16 * g + l15;
        int i = P / 224;
        int j = P - i * 224;
        bool valid = j < NH;
        float mx = fmaxf(fmaxf(wmax[0][g * 16 + l15], wmax[1][g * 16 + l15]),
                         fmaxf(wmax[2][g * 16 + l15], wmax[3][g * 16 + l15]));
        float inv = 1.f / (mx + 1e-9f);
#pragma unroll
        for (int r = 0; r < 4; r++) {
            float tv = fmaxf(acc[g][r], 0.f) * inv;
            float t2 = tv * tv;
            tv = t2 * t2 * tv;
            if (valid) {
                int oc = 16 * w + quad * 4 + r;
                out[oc * OUT_PLANE + i * NH + j] = tv;
                yb[oc * KP2 + P] = f2bf(tv);
            }
        }
    }
}

// ---- Kernel 2: LDS-staged GEMM y^T @ [xf|y|1] (R12/R15 config, shifted-copy B) ----
__global__ __launch_bounds__(256) void gemm_kernel(const uint16_t* __restrict__ yb,
                                                   const uint16_t* __restrict__ xs,
                                                   const uint16_t* __restrict__ ones,
                                                   float* __restrict__ Mpart) {
    __shared__ uint16_t As[2][64 * 40];
    __shared__ uint16_t Bs[2][64 * 40];
    const int tid = threadIdx.x;
    const int lane = tid & 63;
    const int w = tid >> 6;
    const int l15 = lane & 15;
    const int quad = lane >> 4;
    const int kg = quad * 8;
    const int b = blockIdx.x;
    const int xcd = b & 7;
    const int t8 = b >> 3;
    const int ntile = t8 & 7;
    const int chunk = xcd + 8 * (t8 >> 3);
    const int k0 = chunk * CK;

    const int sr = tid >> 2;
    const int sseg = (tid & 3) * 8;
    const uint16_t* pa = yb + sr * KP2 + k0 + sseg;

    int n_g = ntile * 64 + sr;
    const uint16_t* pbase;
    if (n_g < 400) {
        int c = n_g / 25;
        int r = n_g - 25 * c;
        int ki = r / 5;
        int kj = r - 5 * ki;
        pbase = xs + (kj * 16 + c) * XS + ki * 224;
    } else if (n_g < 464) {
        pbase = yb + (n_g - 400) * KP2;
    } else if (n_g == 464) {
        pbase = ones;
    } else {
        pbase = yb;  // dead column
    }
    const uint16_t* pb = pbase + k0 + sseg;

    floatx4 acc[4];
#pragma unroll
    for (int i = 0; i < 4; i++) acc[i] = (floatx4){0.f, 0.f, 0.f, 0.f};

    uint4 ra = *(const uint4*)pa;
    uint4 rb = *(const uint4*)pb;

    for (int s = 0; s < 25; s++) {
        const int p = s & 1;
        *(uint4*)&As[p][sr * 40 + sseg] = ra;
        *(uint4*)&Bs[p][sr * 40 + sseg] = rb;
        __syncthreads();
        if (s + 1 < 25) {
            pa += 32;
            pb += 32;
            ra = *(const uint4*)pa;
            rb = *(const uint4*)pb;
        }
        short8 af = *(const short8*)&As[p][(16 * w + l15) * 40 + kg];
#pragma unroll
        for (int ng = 0; ng < 4; ng++) {
            short8 bf = *(const short8*)&Bs[p][(16 * ng + l15) * 40 + kg];
            acc[ng] = __builtin_amdgcn_mfma_f32_16x16x32_bf16(af, bf, acc[ng], 0, 0, 0);
        }
        __syncthreads();
    }

    float* dst = Mpart + chunk * PSTRIDE;
#pragma unroll
    for (int ng = 0; ng < 4; ng++) {
        int col = ntile * 64 + ng * 16 + l15;
        if (col < 465) {
#pragma unroll
            for (int r = 0; r < 4; r++)
                dst[(16 * w + quad * 4 + r) * 512 + col] = acc[ng][r];
        }
    }
}

// ---- Kernel 3: FUSED reduce + finalize: Mpart -> Wout, expout ----
__global__ __launch_bounds__(256) void finalize_w_kernel(const float* __restrict__ W,
                                                         const float* __restrict__ Mpart,
                                                         const float* __restrict__ exp_avg,
                                                         float* __restrict__ Wout,
                                                         float* __restrict__ expout) {
    __shared__ float gfps[OUT_CH];
    __shared__ float ytys[2][OUT_CH];
    const int tid = threadIdx.x;
    const int bid = blockIdx.x;
    const int first_o = (bid * 256) / 400;

    if (tid < OUT_CH) {  // colsum -> exp_new -> gfp
        int o = tid;
        float cs = 0.f;
#pragma unroll 8
        for (int ch = 0; ch < NCHUNK; ch++) cs += Mpart[ch * PSTRIDE + o * 512 + 464];
        float e = GAMMA_F * exp_avg[o] + ONE_MINUS_GAMMA * (cs / (float)NB_TILES);
        float s = e;
        for (int off = 32; off; off >>= 1) s += __shfl_down(s, off);
        s = __shfl(s, 0);
        float A = e / (s / (float)OUT_CH);
        gfps[o] = EPS_F * tanhf(-EPS_F * (A - 1.f)) + 1.f;
        if (bid == 0) expout[o] = e;
    }
    if (tid >= 128) {  // the <=2 yty rows this block needs
        int t = tid - 128;
        int orow = first_o + (t >> 6);
        int k = t & 63;
        float s = 0.f;
        if (orow < OUT_CH) {
#pragma unroll 8
            for (int ch = 0; ch < NCHUNK; ch++) s += Mpart[ch * PSTRIDE + orow * 512 + 400 + k];
        }
        ytys[t >> 6][k] = s;
    }
    __syncthreads();

    int idx = bid * 256 + tid;
    int o = idx / 400;
    int q = idx - o * 400;
    float Mv = 0.f;
#pragma unroll 8
    for (int ch = 0; ch < NCHUNK; ch++) Mv += Mpart[ch * PSTRIDE + o * 512 + q];
    const float* yrow = ytys[o - first_o];
    float dot = 0.f;
#pragma unroll 8
    for (int k = 0; k < OUT_CH; k++) dot = fmaf(yrow[k], W[k * 400 + q], dot);
    float wv = W[idx] + LR_OVER_NB * (Mv - dot);
    wv = fmaxf(wv, 0.f);
    float gp = gfps[o];
    float pos = (wv > 0.f ? wv : 0.f) * gp;
    float neg = (wv < 0.f ? wv : 0.f) / gp;
    Wout[idx] = pos + neg;
}

extern "C" void kernel_launch(void* const* d_in, const int* in_sizes, int n_in,
                              void* d_out, int out_size, void* d_ws, size_t ws_size,
                              hipStream_t stream) {
    const float* x = (const float*)d_in[0];
    const float* W = (const float*)d_in[1];
    const float* exp_avg = (const float*)d_in[2];
    float* out = (float*)d_out;

    float* wsf = (float*)d_ws;
    float* Mpart = wsf + 29760;                 // 64*32768 floats
    // conv-side buffers overlaid on Mpart (dead until gemm writes it)
    uint16_t* xth = (uint16_t*)Mpart;           // 50304*16
    uint16_t* xtl = xth + XTROWS * 16;          // 50304*16
    uint16_t* wrh = xtl + XTROWS * 16;          // 26624
    uint16_t* wrl = wrh + 26624;                // 26624
    uint16_t* ybf = (uint16_t*)(wsf + 29760 + NCHUNK * PSTRIDE);  // 64*51200 bf16
    uint16_t* xsb = ybf + OUT_CH * KP2;                            // 5*16*52224 bf16
    uint16_t* ones = xsb + 5 * 16 * XS;                            // 51264 bf16

    float* Wout = out + OUT_CH * OUT_PLANE;
    float* expout = Wout + OUT_CH * IN_CH * KER * KER;

    prepa_kernel<<<301, 256, 0, stream>>>(x, xth, xtl, W, wrh, wrl);
    conv_prep_kernel<<<770 + 4080, 256, 0, stream>>>(xth, xtl, wrh, wrl, out, ybf, x, xsb, ones);
    gemm_kernel<<<512, 256, 0, stream>>>(ybf, xsb, ones, Mpart);
    finalize_w_kernel<<<100, 256, 0, stream>>>(W, Mpart, exp_avg, Wout, expout);
}